// Round 7
// baseline (417.313 us; speedup 1.0000x reference)
//
#include <hip/hip_runtime.h>

typedef _Float16 half_t;
typedef __attribute__((ext_vector_type(8))) _Float16 halfx8;
typedef __attribute__((ext_vector_type(4))) float floatx4;

#define N_NODES 200000
#define N_EDGES 800000
#define NPOS    16384     // 128*128 feature-map positions
#define KIN     484       // 480 backbone + 4 seg channels

// degree binning: 16 ranges x 12500 counters, 4 edge chunks
#define NRANGE  16
#define RSIZE   12500
#define NCHUNK  4
#define C_I4    100000    // int4s per chunk (400000 int4 total / 4)

// ws layout (bytes)
#define WS_DEGP  0          // 16*4*12500*u32 = 3,200,000
#define WS_DEG   3200000    // 200000*u32 = 800,000
#define WS_MAXD  4000000    // 64
#define WS_W2H   4000064    // 128*128 fp16 = 32768
#define WS_W1H   4032832    // 128*512 fp16 = 131072
#define WS_U     4163904    // 16384*128 fp16 = 4 MiB (end ~8.36 MB)

// ---------------------------------------------------------------- k0 (tiny)
__global__ __launch_bounds__(256) void k0(const float* __restrict__ W1,
                                          const float* __restrict__ W2,
                                          half_t* __restrict__ w2h,
                                          half_t* __restrict__ w1h) {
  const int tid = threadIdx.x, bid = blockIdx.x;
  if (bid == 0) {
    for (int i = tid; i < 128 * 128; i += 256) w2h[i] = (half_t)W2[i];
  } else {
    int j = bid - 1;
    const float* row = W1 + j * 488 + 2;
    int k1 = tid, k2 = tid + 256;
    w1h[j * 512 + k1] = (half_t)((k1 < KIN) ? row[k1] : 0.f);
    w1h[j * 512 + k2] = (half_t)((k2 < KIN) ? row[k2] : 0.f);
  }
}

// ---------------------------------------------------------------- k1
// blocks [0,64):   LDS-histogram degree (range r = bid>>2, chunk c = bid&3)
// blocks [64,320): U-GEMM (round-5/6 verified body, A-frags from w1h)
__global__ __launch_bounds__(256) void k1(const half_t* __restrict__ w1h,
                                          const float* __restrict__ bb,
                                          const float* __restrict__ seg,
                                          const int* __restrict__ e,
                                          unsigned* __restrict__ degp,
                                          half_t* __restrict__ U) {
  __shared__ __align__(16) char smem[50000];   // max(hist 50000, Bl+Ol 22528)
  const int tid = threadIdx.x;
  const int bid = blockIdx.x;

  if (bid < 64) {
    // ---- degree histogram, zero global atomics
    unsigned* hist = (unsigned*)smem;
    const int r = bid >> 2, c = bid & 3;
    for (int i = tid; i < RSIZE; i += 256) hist[i] = 0;
    __syncthreads();
    const unsigned base = (unsigned)(r * RSIZE);
    const int4* ep = (const int4*)e + c * C_I4;
    for (int t = 0; t < 391; ++t) {
      int idx = t * 256 + tid;
      if (idx < C_I4) {
        int4 v = ep[idx];
        unsigned l0 = (unsigned)v.x - base;
        unsigned l1 = (unsigned)v.y - base;
        unsigned l2 = (unsigned)v.z - base;
        unsigned l3 = (unsigned)v.w - base;
        if (l0 < (unsigned)RSIZE) atomicAdd(&hist[l0], 1u);
        if (l1 < (unsigned)RSIZE) atomicAdd(&hist[l1], 1u);
        if (l2 < (unsigned)RSIZE) atomicAdd(&hist[l2], 1u);
        if (l3 < (unsigned)RSIZE) atomicAdd(&hist[l3], 1u);
      }
    }
    __syncthreads();
    unsigned* dst = degp + (r * NCHUNK + c) * RSIZE;
    for (int i = tid; i < RSIZE; i += 256) dst[i] = hist[i];
  } else {
    // ---- U-GEMM (verified body)
    half_t* Bl = (half_t*)smem;            // [64][40]
    half_t* Ol = (half_t*)(smem + 5120);   // [64][136]
    const int n0 = (bid - 64) * 64;
    const int wave = tid >> 6, lane = tid & 63;
    const int l15 = lane & 15, q8 = (lane >> 4) * 8;

    floatx4 acc[2][4];
    for (int mt = 0; mt < 2; ++mt)
      for (int nt = 0; nt < 4; ++nt)
        acc[mt][nt] = (floatx4){0.f, 0.f, 0.f, 0.f};

    for (int kb = 0; kb < 512; kb += 32) {
      halfx8 af[2];
      for (int mt = 0; mt < 2; ++mt)
        af[mt] = *(const halfx8*)&w1h[(wave * 32 + mt * 16 + l15) * 512 + kb + q8];

      {
        int kk = tid >> 3, nc = (tid & 7) * 8;
        int k = kb + kk;
        float vals[8];
        if (k < 480) {
          const float* src = bb + k * NPOS + n0 + nc;
          float4 a = *(const float4*)(src);
          float4 b = *(const float4*)(src + 4);
          vals[0] = a.x; vals[1] = a.y; vals[2] = a.z; vals[3] = a.w;
          vals[4] = b.x; vals[5] = b.y; vals[6] = b.z; vals[7] = b.w;
        } else if (k < KIN) {
          const float* src = seg + (k - 480) * NPOS + n0 + nc;
          float4 a = *(const float4*)(src);
          float4 b = *(const float4*)(src + 4);
          vals[0] = a.x; vals[1] = a.y; vals[2] = a.z; vals[3] = a.w;
          vals[4] = b.x; vals[5] = b.y; vals[6] = b.z; vals[7] = b.w;
        } else {
          for (int i = 0; i < 8; ++i) vals[i] = 0.f;
        }
        for (int i = 0; i < 8; ++i) Bl[(nc + i) * 40 + kk] = (half_t)vals[i];
      }
      __syncthreads();

      halfx8 bf[4];
      for (int nt = 0; nt < 4; ++nt)
        bf[nt] = *(const halfx8*)&Bl[(nt * 16 + l15) * 40 + q8];
      for (int mt = 0; mt < 2; ++mt)
        for (int nt = 0; nt < 4; ++nt)
          acc[mt][nt] = __builtin_amdgcn_mfma_f32_16x16x32_f16(af[mt], bf[nt],
                                                               acc[mt][nt], 0, 0, 0);
      __syncthreads();
    }

    for (int mt = 0; mt < 2; ++mt)
      for (int nt = 0; nt < 4; ++nt)
        for (int r2 = 0; r2 < 4; ++r2) {
          int j = wave * 32 + mt * 16 + (lane >> 4) * 4 + r2;
          int n = nt * 16 + l15;
          Ol[n * 136 + j] = (half_t)acc[mt][nt][r2];
        }
    __syncthreads();
    for (int it = 0; it < 4; ++it) {
      int idx = tid + it * 256;            // 0..1023
      int n = idx >> 4, c8 = (idx & 15) * 8;
      *(halfx8*)(U + (long)(n0 + n) * 128 + c8) = *(const halfx8*)&Ol[n * 136 + c8];
    }
  }
}

// ---------------------------------------------------------------- k2 (tiny)
// deg[n] = sum of 4 chunk copies; max -> atomicMax. Exact integers.
__global__ __launch_bounds__(256) void k2(const unsigned* __restrict__ degp,
                                          unsigned* __restrict__ deg,
                                          unsigned* __restrict__ maxd) {
  const int tid = threadIdx.x;
  unsigned m = 0;
  for (int it = 0; it < 4; ++it) {
    int n = blockIdx.x * 1024 + it * 256 + tid;
    if (n < N_NODES) {
      int r = n / RSIZE, local = n - r * RSIZE;
      const unsigned* p = degp + r * (NCHUNK * RSIZE) + local;
      unsigned s = p[0] + p[RSIZE] + p[2 * RSIZE] + p[3 * RSIZE];
      deg[n] = s;
      m = max(m, s);
    }
  }
  for (int off = 32; off > 0; off >>= 1) {
    unsigned o = (unsigned)__shfl_down((int)m, off);
    m = max(m, o);
  }
  if ((tid & 63) == 0) atomicMax(maxd, m);
}

// ---------------------------------------------------------------- k_main
// Phase A re-mapped: 16 lanes share a node, each lane owns 8 columns ->
// halfx8 corner loads (16B/lane) + halfx8 At writes. Same per-z expression
// order as rounds 1/5/6 -> bit-identical. Phase B/epilogue = round 6.
__global__ __launch_bounds__(256) void k_main(const float* __restrict__ vertices,
                                              const float* __restrict__ W1,
                                              const float* __restrict__ b1,
                                              const float* __restrict__ b2,
                                              const unsigned* __restrict__ deg,
                                              const unsigned* __restrict__ maxd,
                                              const half_t* __restrict__ U,
                                              const half_t* __restrict__ w2h,
                                              float* __restrict__ out) {
  __shared__ half_t At[64 * 136];    // h1 tile [node][j], stride 136
  __shared__ half_t W2l[128 * 72];   // W2 k-half [jout][64+8]
  __shared__ int   pPos[64];
  __shared__ float pW[4][64];
  __shared__ float pE[4][64];
  __shared__ float WexL[6 * 128];    // W1 cols 0,1,486,487 + b1 + b2

  const int tid = threadIdx.x;
  const int nodeBase = blockIdx.x * 64;

  // stage scalar-feature columns + biases
  if (tid < 128) {
    const float* r = W1 + tid * 488;
    WexL[0 * 128 + tid] = r[0];
    WexL[1 * 128 + tid] = r[1];
    WexL[2 * 128 + tid] = r[486];
    WexL[3 * 128 + tid] = r[487];
    WexL[4 * 128 + tid] = b1[tid];
    WexL[5 * 128 + tid] = b2[tid];
  }

  // per-node params (verified round-5 body)
  if (tid < 64) {
    int n = nodeBase + tid;
    float vx = vertices[2 * n], vy = vertices[2 * n + 1];
    float ix = vx * (127.0f / 512.0f), iy = vy * (127.0f / 512.0f);
    float fx = floorf(ix), fy = floorf(iy);
    float wx = ix - fx, wy = iy - fy;
    int x0 = min(max((int)fx, 0), 127);
    int y0 = min(max((int)fy, 0), 127);
    pPos[tid] = y0 * 128 + x0;
    pW[0][tid] = (1.f - wx) * (1.f - wy);
    pW[1][tid] = wx * (1.f - wy);
    pW[2][tid] = (1.f - wx) * wy;
    pW[3][tid] = wx * wy;
    pE[0][tid] = vx * (1.f / 512.f);
    pE[1][tid] = vy * (1.f / 512.f);
    float md = (float)(*maxd) + 1e-6f;
    pE[2][tid] = (float)deg[n] / md;
    float dx = fminf(vx, 512.f - vx), dy = fminf(vy, 512.f - vy);
    pE[3][tid] = fminf(dx, dy) * (1.f / 256.f);
  }
  __syncthreads();

  // ---- phase A: h1 -> At. lane group: nn = tid>>4 (node-sub), 8 cols each
  {
    const int nn = tid >> 4;            // 0..15
    const int cg = (tid & 15) * 8;      // column group base
    for (int g = 0; g < 4; ++g) {
      int ln = g * 16 + nn;
      int pos = pPos[ln];
      float w00 = pW[0][ln], w01 = pW[1][ln], w10 = pW[2][ln], w11 = pW[3][ln];
      float cx = pE[0][ln], cy = pE[1][ln], dn = pE[2][ln], db = pE[3][ln];
      const half_t* base = U + (long)pos * 128 + cg;
      halfx8 u00 = *(const halfx8*)(base);
      halfx8 u01 = *(const halfx8*)(base + 128);
      halfx8 u10 = *(const halfx8*)(base + 16384);
      halfx8 u11 = *(const halfx8*)(base + 16512);
      float c0[8], c1[8], c2[8], c3[8], bv[8];
      *(float4*)&c0[0] = *(const float4*)&WexL[0 * 128 + cg];
      *(float4*)&c0[4] = *(const float4*)&WexL[0 * 128 + cg + 4];
      *(float4*)&c1[0] = *(const float4*)&WexL[1 * 128 + cg];
      *(float4*)&c1[4] = *(const float4*)&WexL[1 * 128 + cg + 4];
      *(float4*)&c2[0] = *(const float4*)&WexL[2 * 128 + cg];
      *(float4*)&c2[4] = *(const float4*)&WexL[2 * 128 + cg + 4];
      *(float4*)&c3[0] = *(const float4*)&WexL[3 * 128 + cg];
      *(float4*)&c3[4] = *(const float4*)&WexL[3 * 128 + cg + 4];
      *(float4*)&bv[0] = *(const float4*)&WexL[4 * 128 + cg];
      *(float4*)&bv[4] = *(const float4*)&WexL[4 * 128 + cg + 4];
      halfx8 h;
#pragma unroll
      for (int i = 0; i < 8; ++i) {
        float z = bv[i] + c0[i] * cx + c1[i] * cy + c2[i] * dn + c3[i] * db
                + w00 * (float)u00[i] + w01 * (float)u01[i]
                + w10 * (float)u10[i] + w11 * (float)u11[i];
        h[i] = (half_t)fmaxf(z, 0.f);
      }
      *(halfx8*)&At[ln * 136 + cg] = h;
    }
  }
  __syncthreads();

  // ---- phase B: two W2 k-halves through one LDS buffer (round-6 verbatim)
  const int wave = tid >> 6, lane = tid & 63;
  const int l15 = lane & 15, q4 = lane >> 4;
  floatx4 acc[8];
  for (int t = 0; t < 8; ++t) acc[t] = (floatx4){0.f, 0.f, 0.f, 0.f};

  for (int h = 0; h < 2; ++h) {
    __syncthreads();
    for (int it = 0; it < 4; ++it) {
      int idx = tid + it * 256;            // 0..1023
      int r = idx >> 3, c8 = (idx & 7) * 8;
      *(halfx8*)&W2l[r * 72 + c8] = *(const halfx8*)&w2h[r * 128 + h * 64 + c8];
    }
    __syncthreads();
    for (int ks = 0; ks < 64; ks += 32) {
      halfx8 af = *(const halfx8*)&At[(wave * 16 + l15) * 136 + h * 64 + ks + q4 * 8];
      for (int t = 0; t < 8; ++t) {
        halfx8 bf = *(const halfx8*)&W2l[(t * 16 + l15) * 72 + ks + q4 * 8];
        acc[t] = __builtin_amdgcn_mfma_f32_16x16x32_f16(af, bf, acc[t], 0, 0, 0);
      }
    }
  }

  for (int t = 0; t < 8; ++t) {
    int col = t * 16 + l15;
    float bias = WexL[5 * 128 + col];
    int row0 = nodeBase + wave * 16 + q4 * 4;
    for (int r = 0; r < 4; ++r)
      out[(long)(row0 + r) * 128 + col] = fmaxf(acc[t][r] + bias, 0.f);
  }
}

// ---------------------------------------------------------------- launch
extern "C" void kernel_launch(void* const* d_in, const int* in_sizes, int n_in,
                              void* d_out, int out_size, void* d_ws, size_t ws_size,
                              hipStream_t stream) {
  const float* vertices = (const float*)d_in[0];
  const float* bb       = (const float*)d_in[1];
  const float* seg      = (const float*)d_in[2];
  const int*   edges    = (const int*)d_in[3];
  const float* W1       = (const float*)d_in[4];
  const float* b1       = (const float*)d_in[5];
  const float* W2       = (const float*)d_in[6];
  const float* b2       = (const float*)d_in[7];

  char* ws = (char*)d_ws;
  unsigned* degp = (unsigned*)(ws + WS_DEGP);
  unsigned* deg  = (unsigned*)(ws + WS_DEG);
  unsigned* maxd = (unsigned*)(ws + WS_MAXD);
  half_t*   w2h  = (half_t*)(ws + WS_W2H);
  half_t*   w1h  = (half_t*)(ws + WS_W1H);
  half_t*   U    = (half_t*)(ws + WS_U);
  float*    outp = (float*)d_out;

  hipMemsetAsync(ws + WS_MAXD, 0, 64, stream);   // maxd only
  k0<<<129, 256, 0, stream>>>(W1, W2, w2h, w1h);
  k1<<<320, 256, 0, stream>>>(w1h, bb, seg, edges, degp, U);
  k2<<<196, 256, 0, stream>>>(degp, deg, maxd);
  k_main<<<3125, 256, 0, stream>>>(vertices, W1, b1, b2, deg, maxd, U, w2h, outp);
}